// Round 5
// baseline (288.742 us; speedup 1.0000x reference)
//
#include <hip/hip_runtime.h>
#include <math.h>

// Problem constants
#define T_SEQ 4096
#define CDIM  768
#define NH    12
#define HD    64
#define BATCH 2
#define MROWS (BATCH * T_SEQ)   // 8192
#define N3C   (3 * CDIM)        // 2304
#define HEADS_TOTAL (BATCH * NH)                       // 24
#define QKV_ELEMS   ((size_t)HEADS_TOTAL * T_SEQ * HD) // 6,291,456

// Q pre-scale: 1/sqrt(64) * log2(e)  (softmax done in base-2; exp2 is the
// native v_exp_f32 — saves the ln2 multiply inside __expf)
#define QSCALE 0.18033688011112042f

typedef __bf16 bf16x8 __attribute__((ext_vector_type(8)));
typedef __bf16 bf16x4 __attribute__((ext_vector_type(4)));
typedef __bf16 bf16x2 __attribute__((ext_vector_type(2)));
typedef float  f32x4  __attribute__((ext_vector_type(4)));

typedef __attribute__((address_space(1))) const void as1_cvoid;
typedef __attribute__((address_space(3))) void as3_void;

__device__ __forceinline__ void gl16(const void* g, void* l) {
  __builtin_amdgcn_global_load_lds((as1_cvoid*)g, (as3_void*)l, 16, 0, 0);
}

// ---------------------------------------------------------------------------
// Prep kernels: fp32 -> bf16 cast (x) and transpose-cast (weights).
// ---------------------------------------------------------------------------
__global__ __launch_bounds__(256) void cast_x_kernel(
    const float* __restrict__ x, __bf16* __restrict__ xb) {
  int i = (blockIdx.x * 256 + threadIdx.x) * 8;
  float4 a = *(const float4*)&x[i];
  float4 b = *(const float4*)&x[i + 4];
  bf16x8 o;
  o[0] = (__bf16)a.x; o[1] = (__bf16)a.y; o[2] = (__bf16)a.z; o[3] = (__bf16)a.w;
  o[4] = (__bf16)b.x; o[5] = (__bf16)b.y; o[6] = (__bf16)b.z; o[7] = (__bf16)b.w;
  *(bf16x8*)&xb[i] = o;
}

__global__ __launch_bounds__(256) void tcast_kernel(
    const float* __restrict__ W, __bf16* __restrict__ Wt, int K, int N) {
  __shared__ float tile[64][65];
  const int t  = threadIdx.x;
  const int k0 = blockIdx.y * 64, n0 = blockIdx.x * 64;
  const int r  = t >> 4, c4 = (t & 15) << 2;
#pragma unroll
  for (int i = 0; i < 4; ++i) {
    float4 v = *(const float4*)&W[(size_t)(k0 + r + i * 16) * N + n0 + c4];
    tile[r + i * 16][c4 + 0] = v.x; tile[r + i * 16][c4 + 1] = v.y;
    tile[r + i * 16][c4 + 2] = v.z; tile[r + i * 16][c4 + 3] = v.w;
  }
  __syncthreads();
#pragma unroll
  for (int i = 0; i < 4; ++i) {
    int nr = r + i * 16;
    bf16x4 o;
    o[0] = (__bf16)tile[c4 + 0][nr]; o[1] = (__bf16)tile[c4 + 1][nr];
    o[2] = (__bf16)tile[c4 + 2][nr]; o[3] = (__bf16)tile[c4 + 3][nr];
    *(bf16x4*)&Wt[(size_t)(n0 + nr) * K + k0 + c4] = o;
  }
}

// ---------------------------------------------------------------------------
// m97-style bf16 MFMA GEMM main loop (R4-validated, unchanged).
// ---------------------------------------------------------------------------
__device__ __forceinline__ void mm_loop(const __bf16* __restrict__ A,
                                        const __bf16* __restrict__ Bt,
                                        int m0, int n0, __bf16* smem,
                                        f32x4 acc[4][4]) {
  const int t = threadIdx.x, wv = t >> 6, lane = t & 63;
  const int g2 = lane >> 4, c = lane & 15;
  __bf16* At = smem;          // [128][32]
  __bf16* Bs = smem + 4096;   // [128][32]
  const int ch0 = wv * 64 + lane;
  const int ch1 = 256 + ch0;
  const __bf16* gA0 = A  + (size_t)(m0 + (ch0 >> 2)) * CDIM + ((ch0 & 3) << 3);
  const __bf16* gA1 = A  + (size_t)(m0 + (ch1 >> 2)) * CDIM + ((ch1 & 3) << 3);
  const __bf16* gB0 = Bt + (size_t)(n0 + (ch0 >> 2)) * CDIM + ((ch0 & 3) << 3);
  const __bf16* gB1 = Bt + (size_t)(n0 + (ch1 >> 2)) * CDIM + ((ch1 & 3) << 3);
  __bf16* lA0 = At + (size_t)(wv * 64) * 8;
  __bf16* lA1 = At + (size_t)(256 + wv * 64) * 8;
  __bf16* lB0 = Bs + (size_t)(wv * 64) * 8;
  __bf16* lB1 = Bs + (size_t)(256 + wv * 64) * 8;
  const int mw = (wv & 1) << 6, nw = (wv >> 1) << 6;

  for (int kk = 0; kk < CDIM / 32; ++kk) {
    __syncthreads();
    gl16(gA0, lA0); gl16(gA1, lA1);
    gl16(gB0, lB0); gl16(gB1, lB1);
    gA0 += 32; gA1 += 32; gB0 += 32; gB1 += 32;
    __syncthreads();
    bf16x8 af[4], bfr[4];
#pragma unroll
    for (int mq = 0; mq < 4; ++mq)
      af[mq] = *(const bf16x8*)&At[(size_t)(mw + mq * 16 + c) * 32 + (g2 << 3)];
#pragma unroll
    for (int nq = 0; nq < 4; ++nq)
      bfr[nq] = *(const bf16x8*)&Bs[(size_t)(nw + nq * 16 + c) * 32 + (g2 << 3)];
#pragma unroll
    for (int mq = 0; mq < 4; ++mq)
#pragma unroll
      for (int nq = 0; nq < 4; ++nq)
        acc[mq][nq] = __builtin_amdgcn_mfma_f32_16x16x32_bf16(
            af[mq], bfr[nq], acc[mq][nq], 0, 0, 0);
  }
  __syncthreads();
}

// ---------------------------------------------------------------------------
// Kernel 1: qkv projection (bf16 MFMA) + re-tile epilogue (R4-validated).
// Q now pre-scaled by QSCALE (base-2 softmax).
// ---------------------------------------------------------------------------
__global__ __launch_bounds__(256) void qkv_mm_kernel(
    const __bf16* __restrict__ xb, const __bf16* __restrict__ Wt,
    const float* __restrict__ bias, __bf16* __restrict__ Qw,
    __bf16* __restrict__ Kw, __bf16* __restrict__ Vtw) {
  __shared__ __align__(16) __bf16 smem[18432];
  f32x4 acc[4][4];
#pragma unroll
  for (int i = 0; i < 4; ++i)
#pragma unroll
    for (int j = 0; j < 4; ++j) acc[i][j] = (f32x4){0.f, 0.f, 0.f, 0.f};

  const int m0 = blockIdx.y * 128, n0 = blockIdx.x * 128;
  mm_loop(xb, Wt, m0, n0, smem, acc);

  const int t = threadIdx.x, wv = t >> 6, lane = t & 63;
  const int g2 = lane >> 4, c = lane & 15;
  const int sel = n0 / CDIM;
  const int nn0 = n0 - sel * CDIM;
  const int h   = (nn0 >> 6) + (wv >> 1);
  const int mbase = m0 + ((wv & 1) << 6);
  const int b = mbase >> 12, tp0 = mbase & 4095;
  const int bh = b * NH + h;
  __bf16* Ep = smem + wv * 4608;
  float bcol[4];
#pragma unroll
  for (int nq = 0; nq < 4; ++nq)
    bcol[nq] = bias[n0 + ((wv >> 1) << 6) + nq * 16 + c];

  const int r8 = lane >> 3, c8 = (lane & 7) << 3;
  if (sel < 2) {
    const float scl = (sel == 0) ? QSCALE : 1.0f;
#pragma unroll
    for (int mq = 0; mq < 4; ++mq)
#pragma unroll
      for (int nq = 0; nq < 4; ++nq)
#pragma unroll
        for (int r = 0; r < 4; ++r)
          Ep[(size_t)(mq * 16 + (g2 << 2) + r) * 72 + nq * 16 + c] =
              (__bf16)((acc[mq][nq][r] + bcol[nq]) * scl);
    asm volatile("s_waitcnt lgkmcnt(0)" ::: "memory");
    __bf16* dst = (sel == 0) ? Qw : Kw;
#pragma unroll
    for (int p = 0; p < 8; ++p) {
      int row = p * 8 + r8;
      bf16x8 v = *(const bf16x8*)&Ep[(size_t)row * 72 + c8];
      *(bf16x8*)&dst[((size_t)bh * T_SEQ + tp0 + row) * HD + c8] = v;
    }
  } else {
#pragma unroll
    for (int mq = 0; mq < 4; ++mq)
#pragma unroll
      for (int nq = 0; nq < 4; ++nq)
#pragma unroll
        for (int r = 0; r < 4; ++r)
          Ep[(size_t)(nq * 16 + c) * 72 + mq * 16 + (g2 << 2) + r] =
              (__bf16)(acc[mq][nq][r] + bcol[nq]);
    asm volatile("s_waitcnt lgkmcnt(0)" ::: "memory");
#pragma unroll
    for (int p = 0; p < 8; ++p) {
      int d = p * 8 + r8;
      bf16x8 v = *(const bf16x8*)&Ep[(size_t)d * 72 + c8];
      *(bf16x8*)&Vtw[((size_t)bh * HD + d) * T_SEQ + tp0 + c8] = v;
    }
  }
}

// ---------------------------------------------------------------------------
// Kernel 2: causal flash attention, bf16 MFMA, double-buffered LDS staging.
// grid = (bh = 24, pi = 32): flat block id = pi*24 + bh, and 24 % 8 == 0, so
// under round-robin dispatch ALL 32 q-tile blocks of one bh land on the SAME
// XCD -> 3 bh/XCD = 3 MB K+V working set < 4 MB L2. This converts the R4
// 318 MB cross-fabric re-fetch into L2 hits.
// Softmax in base-2 (Q pre-scaled by log2e/8; exp2f = native v_exp_f32).
// ---------------------------------------------------------------------------
struct Stage { bf16x8 k0, k1, v0, v1; };

__device__ __forceinline__ void issue_stage(const __bf16* __restrict__ Kb,
                                            const __bf16* __restrict__ Vb,
                                            int kt, int wv, int lane, Stage& sg) {
  const int r8 = lane >> 3;
  const int cc = (lane & 7) << 3;
  const int row0 = (wv << 4) + r8;
  const int row1 = row0 + 8;
  sg.k0 = *(const bf16x8*)&Kb[(size_t)(kt * 64 + row0) * HD + cc];
  sg.k1 = *(const bf16x8*)&Kb[(size_t)(kt * 64 + row1) * HD + cc];
  sg.v0 = *(const bf16x8*)&Vb[(size_t)row0 * T_SEQ + kt * 64 + cc];
  sg.v1 = *(const bf16x8*)&Vb[(size_t)row1 * T_SEQ + kt * 64 + cc];
}

__device__ __forceinline__ void write_stage(__bf16 (*KT)[72], __bf16 (*VT)[72],
                                            int wv, int lane, const Stage& sg) {
  const int r8 = lane >> 3;
  const int cc = (lane & 7) << 3;
  const int row0 = (wv << 4) + r8;
  const int row1 = row0 + 8;
  *(bf16x8*)&KT[row0][cc] = sg.k0;
  *(bf16x8*)&KT[row1][cc] = sg.k1;
  *(bf16x8*)&VT[row0][cc] = sg.v0;
  *(bf16x8*)&VT[row1][cc] = sg.v1;
}

__global__ __launch_bounds__(256) void attn_kernel(
    const __bf16* __restrict__ Q, const __bf16* __restrict__ K,
    const __bf16* __restrict__ Vt, __bf16* __restrict__ O) {
  __shared__ __align__(16) __bf16 KT[2][64][72];
  __shared__ __align__(16) __bf16 VT[2][64][72];
  __shared__ __align__(16) __bf16 Pl[4][16][72];

  const int t    = threadIdx.x;
  const int wv   = t >> 6;
  const int lane = t & 63;
  const int g2   = lane >> 4;
  const int c    = lane & 15;
  const int bh   = blockIdx.x;      // XCD-locality: stride-24 => same XCD per bh
  const int pi   = blockIdx.y;

  const __bf16* Qb = Q  + (size_t)bh * T_SEQ * HD;
  const __bf16* Kb = K  + (size_t)bh * T_SEQ * HD;
  const __bf16* Vb = Vt + (size_t)bh * HD * T_SEQ;
  __bf16* plw = &Pl[wv][c][0];

  const int b = bh / NH, hh = bh % NH;

#pragma unroll 1
  for (int half = 0; half < 2; ++half) {
    const int qt = half ? (63 - pi) : pi;
    const int qw = qt * 64 + wv * 16;

    bf16x8 qf0 = *(const bf16x8*)&Qb[(size_t)(qw + c) * HD +      (g2 << 3)];
    bf16x8 qf1 = *(const bf16x8*)&Qb[(size_t)(qw + c) * HD + 32 + (g2 << 3)];

    f32x4 ot[4];
#pragma unroll
    for (int mt = 0; mt < 4; ++mt) ot[mt] = (f32x4){0.f, 0.f, 0.f, 0.f};
    float m_i = -INFINITY, l_i = 0.f;

    Stage sg;
    issue_stage(Kb, Vb, 0, wv, lane, sg);
    write_stage(KT[0], VT[0], wv, lane, sg);
    __syncthreads();

#pragma unroll 1
    for (int kt = 0; kt <= qt; ++kt) {
      const int cur = kt & 1;
      if (kt < qt) issue_stage(Kb, Vb, kt + 1, wv, lane, sg);

      f32x4 S[4];
#pragma unroll
      for (int st = 0; st < 4; ++st) S[st] = (f32x4){0.f, 0.f, 0.f, 0.f};
#pragma unroll
      for (int st = 0; st < 4; ++st) {
        bf16x8 kfa = *(const bf16x8*)&KT[cur][st * 16 + c][(g2 << 3)];
        bf16x8 kfb = *(const bf16x8*)&KT[cur][st * 16 + c][(g2 << 3) + 32];
        S[st] = __builtin_amdgcn_mfma_f32_16x16x32_bf16(kfa, qf0, S[st], 0, 0, 0);
        S[st] = __builtin_amdgcn_mfma_f32_16x16x32_bf16(kfb, qf1, S[st], 0, 0, 0);
      }

      if (kt == qt) {
        const int qloc = (wv << 4) + c;
#pragma unroll
        for (int st = 0; st < 4; ++st)
#pragma unroll
          for (int r = 0; r < 4; ++r)
            if ((st << 4) + (g2 << 2) + r > qloc) S[st][r] = -INFINITY;
      }

      float tmax = -INFINITY;
#pragma unroll
      for (int st = 0; st < 4; ++st)
#pragma unroll
        for (int r = 0; r < 4; ++r) tmax = fmaxf(tmax, S[st][r]);
      tmax = fmaxf(tmax, __shfl_xor(tmax, 16));
      tmax = fmaxf(tmax, __shfl_xor(tmax, 32));
      float m_new = fmaxf(m_i, tmax);
      float alpha = exp2f(m_i - m_new);      // base-2 softmax
      float psum = 0.f;
#pragma unroll
      for (int st = 0; st < 4; ++st)
#pragma unroll
        for (int r = 0; r < 4; ++r) {
          S[st][r] = exp2f(S[st][r] - m_new);
          psum += S[st][r];
        }
      psum += __shfl_xor(psum, 16);
      psum += __shfl_xor(psum, 32);
      l_i = l_i * alpha + psum;
      m_i = m_new;
#pragma unroll
      for (int mt = 0; mt < 4; ++mt)
#pragma unroll
        for (int r = 0; r < 4; ++r) ot[mt][r] *= alpha;

#pragma unroll
      for (int st = 0; st < 4; ++st) {
        bf16x2 p0; p0[0] = (__bf16)S[st][0]; p0[1] = (__bf16)S[st][1];
        bf16x2 p1; p1[0] = (__bf16)S[st][2]; p1[1] = (__bf16)S[st][3];
        *(bf16x2*)&plw[(st << 4) + (g2 << 2)]     = p0;
        *(bf16x2*)&plw[(st << 4) + (g2 << 2) + 2] = p1;
      }
      asm volatile("s_waitcnt lgkmcnt(0)" ::: "memory");
      bf16x8 pf0 = *(const bf16x8*)&plw[     (g2 << 3)];
      bf16x8 pf1 = *(const bf16x8*)&plw[32 + (g2 << 3)];

#pragma unroll
      for (int mt = 0; mt < 4; ++mt) {
        bf16x8 vf0 = *(const bf16x8*)&VT[cur][mt * 16 + c][(g2 << 3)];
        bf16x8 vf1 = *(const bf16x8*)&VT[cur][mt * 16 + c][(g2 << 3) + 32];
        ot[mt] = __builtin_amdgcn_mfma_f32_16x16x32_bf16(vf0, pf0, ot[mt], 0, 0, 0);
        ot[mt] = __builtin_amdgcn_mfma_f32_16x16x32_bf16(vf1, pf1, ot[mt], 0, 0, 0);
      }

      if (kt < qt) write_stage(KT[cur ^ 1], VT[cur ^ 1], wv, lane, sg);
      __syncthreads();
    }

    const float inv = 1.f / l_i;
    __bf16* orow = O + ((size_t)(b * T_SEQ + qw + c)) * CDIM + hh * HD;
#pragma unroll
    for (int mt = 0; mt < 4; ++mt) {
      bf16x4 v;
      v[0] = (__bf16)(ot[mt][0] * inv); v[1] = (__bf16)(ot[mt][1] * inv);
      v[2] = (__bf16)(ot[mt][2] * inv); v[3] = (__bf16)(ot[mt][3] * inv);
      *(bf16x4*)&orow[mt * 16 + (g2 << 2)] = v;
    }
  }
}

// ---------------------------------------------------------------------------
// Kernel 3: out = Ob @ Wprojt^T + b_proj (bf16 MFMA, fp32 out).
// ---------------------------------------------------------------------------
__global__ __launch_bounds__(256) void proj_mm_kernel(
    const __bf16* __restrict__ Ob, const __bf16* __restrict__ Wt,
    const float* __restrict__ bias, float* __restrict__ out) {
  __shared__ __align__(16) __bf16 smem[8192];
  f32x4 acc[4][4];
#pragma unroll
  for (int i = 0; i < 4; ++i)
#pragma unroll
    for (int j = 0; j < 4; ++j) acc[i][j] = (f32x4){0.f, 0.f, 0.f, 0.f};

  const int m0 = blockIdx.y * 128, n0 = blockIdx.x * 128;
  mm_loop(Ob, Wt, m0, n0, smem, acc);

  const int t = threadIdx.x, wv = t >> 6, lane = t & 63;
  const int g2 = lane >> 4, c = lane & 15;
  const int mb = m0 + ((wv & 1) << 6), nb = n0 + ((wv >> 1) << 6);
  float bcol[4];
#pragma unroll
  for (int nq = 0; nq < 4; ++nq) bcol[nq] = bias[nb + nq * 16 + c];
#pragma unroll
  for (int mq = 0; mq < 4; ++mq)
#pragma unroll
    for (int nq = 0; nq < 4; ++nq)
#pragma unroll
      for (int r = 0; r < 4; ++r)
        out[(size_t)(mb + mq * 16 + (g2 << 2) + r) * CDIM + nb + nq * 16 + c] =
            acc[mq][nq][r] + bcol[nq];
}

// ---------------------------------------------------------------------------
extern "C" void kernel_launch(void* const* d_in, const int* in_sizes, int n_in,
                              void* d_out, int out_size, void* d_ws, size_t ws_size,
                              hipStream_t stream) {
  (void)in_sizes; (void)n_in; (void)out_size; (void)ws_size;
  const float* x      = (const float*)d_in[0];
  const float* W_qkv  = (const float*)d_in[1];
  const float* b_qkv  = (const float*)d_in[2];
  const float* W_proj = (const float*)d_in[3];
  const float* b_proj = (const float*)d_in[4];
  float* out = (float*)d_out;

  __bf16* Qw     = (__bf16*)d_ws;
  __bf16* Kw     = Qw  + QKV_ELEMS;
  __bf16* Vtw    = Kw  + QKV_ELEMS;
  __bf16* Ob     = Vtw + QKV_ELEMS;
  __bf16* xb     = Ob  + QKV_ELEMS;
  __bf16* Wqkvt  = xb  + QKV_ELEMS;
  __bf16* Wprojt = Wqkvt + (size_t)CDIM * N3C;

  cast_x_kernel<<<MROWS * CDIM / 2048, 256, 0, stream>>>(x, xb);
  tcast_kernel<<<dim3(N3C / 64, CDIM / 64), 256, 0, stream>>>(
      W_qkv, Wqkvt, CDIM, N3C);
  tcast_kernel<<<dim3(CDIM / 64, CDIM / 64), 256, 0, stream>>>(
      W_proj, Wprojt, CDIM, CDIM);

  qkv_mm_kernel<<<dim3(N3C / 128, MROWS / 128), 256, 0, stream>>>(
      xb, Wqkvt, b_qkv, Qw, Kw, Vtw);

  // grid (bh, pi): all 32 blocks of a bh share one XCD's L2
  attn_kernel<<<dim3(HEADS_TOTAL, 32), 256, 0, stream>>>(Qw, Kw, Vtw, Ob);

  proj_mm_kernel<<<dim3(CDIM / 128, MROWS / 128), 256, 0, stream>>>(
      Ob, Wprojt, b_proj, out);
}